// Round 7
// baseline (263.546 us; speedup 1.0000x reference)
//
#include <hip/hip_runtime.h>
#include <math.h>

#define NN 50000
#define NE 800000
#define D 64
#define NC 40
#define NB_SCAN 196  // ceil(NN/256)

typedef unsigned short u16;
typedef unsigned int u32;

__device__ __forceinline__ float bf16_to_f32(u16 u) {
    return __uint_as_float(((u32)u) << 16);
}
__device__ __forceinline__ u16 f32_to_bf16(float v) {
    u32 x = __float_as_uint(v);
    x += 0x7FFFu + ((x >> 16) & 1u);  // round-to-nearest-even
    return (u16)(x >> 16);
}

// ---------------- CSR build ----------------

// rank[e] = arrival order of edge e at its destination; cnt[i] ends as in-degree.
// 2 edges/thread, int2 loads.
__global__ void count_rank(const int* __restrict__ ei, int* __restrict__ cnt,
                           int* __restrict__ rank) {
    int e = (blockIdx.x * blockDim.x + threadIdx.x) * 2;
    if (e < NE) {
        int2 dd = *(const int2*)&ei[NE + e];
        int r0 = atomicAdd(&cnt[dd.x], 1);
        int r1 = atomicAdd(&cnt[dd.y], 1);
        *(int2*)&rank[e] = make_int2(r0, r1);
    }
}

// Phase A: per-block sums of 256-element chunks of cnt.
__global__ __launch_bounds__(256) void scan_sums(const int* __restrict__ cnt,
                                                 int* __restrict__ partial) {
    __shared__ int s[256];
    int t = threadIdx.x;
    int i = blockIdx.x * 256 + t;
    s[t] = (i < NN) ? cnt[i] : 0;
    __syncthreads();
    for (int off = 128; off > 0; off >>= 1) {
        if (t < off) s[t] += s[t + off];
        __syncthreads();
    }
    if (t == 0) partial[blockIdx.x] = s[0];
}

// Phase B: single small block turns partial sums into exclusive block offsets.
__global__ __launch_bounds__(256) void scan_partials(int* __restrict__ partial) {
    __shared__ int s[256];
    int t = threadIdx.x;
    int v = (t < NB_SCAN) ? partial[t] : 0;
    s[t] = v;
    __syncthreads();
    for (int off = 1; off < 256; off <<= 1) {
        int u = (t >= off) ? s[t - off] : 0;
        __syncthreads();
        s[t] += u;
        __syncthreads();
    }
    if (t < NB_SCAN) partial[t] = s[t] - v;  // exclusive
}

// Phase C: local exclusive scan + block offset; emit rowStart and dinv.
__global__ __launch_bounds__(256) void scan_final(const int* __restrict__ cnt,
                                                  const int* __restrict__ partial,
                                                  int* __restrict__ rowStart,
                                                  float* __restrict__ dinv) {
    __shared__ int s[256];
    int t = threadIdx.x;
    int i = blockIdx.x * 256 + t;
    int v = (i < NN) ? cnt[i] : 0;
    s[t] = v;
    __syncthreads();
    for (int off = 1; off < 256; off <<= 1) {
        int u = (t >= off) ? s[t - off] : 0;
        __syncthreads();
        s[t] += u;
        __syncthreads();
    }
    if (i < NN) {
        rowStart[i] = partial[blockIdx.x] + s[t] - v;
        dinv[i] = rsqrtf((float)v + 1.0f);
    }
    if (i == 0) rowStart[NN] = NE;
}

// No atomics: position = rowStart[dst] + rank[e]. 2 edges/thread.
__global__ void fill_csr(const int* __restrict__ ei, const int* __restrict__ rank,
                         const int* __restrict__ rowStart, u16* __restrict__ csr) {
    int e = (blockIdx.x * blockDim.x + threadIdx.x) * 2;
    if (e < NE) {
        int2 ss = *(const int2*)&ei[e];
        int2 tt = *(const int2*)&ei[NE + e];
        int2 rr = *(const int2*)&rank[e];
        csr[rowStart[tt.x] + rr.x] = (u16)ss.x;
        csr[rowStart[tt.y] + rr.y] = (u16)ss.y;
    }
}

// ---------------- layer-0 dense transform ----------------

// C[row,:] = bf16( (A[row,:] @ W) * dinv[row] )
__global__ __launch_bounds__(256) void gemm64_bf16(const float* __restrict__ A,
                                                   const float* __restrict__ W,
                                                   const float* __restrict__ dinv,
                                                   u16* __restrict__ C) {
    __shared__ float Ws[64 * 64];
    __shared__ float As[4 * 64];
    int tid = threadIdx.x;
    for (int i = tid; i < 64 * 64; i += 256) Ws[i] = W[i];
    int r = tid >> 6, c = tid & 63;
    int row = blockIdx.x * 4 + r;
    if (row < NN) As[r * 64 + c] = A[row * 64 + c];
    __syncthreads();
    if (row < NN) {
        float acc = 0.0f;
#pragma unroll
        for (int k = 0; k < 64; ++k) acc += As[r * 64 + k] * Ws[k * 64 + c];
        C[row * 64 + c] = f32_to_bf16(acc * dinv[row]);
    }
}

// ---------------- fused gather kernels ----------------

// Two-nodes-per-wave gather. n1 = n0+1 so the two CSR rows are CONTIGUOUS:
// one lane-parallel index preload serves both; the consume loop is split at
// the row boundary (no per-edge selects). ~2x loads in flight vs 1 node/wave.
__device__ __forceinline__ void gather2(const int* __restrict__ rowStart,
                                        const u16* __restrict__ csr,
                                        const u16* __restrict__ hs,
                                        int n0, int d,
                                        float& out0, float& out1) {
    int beg0 = rowStart[n0];
    int end0 = rowStart[n0 + 1];
    int end1 = rowStart[n0 + 2];
    int deg0 = end0 - beg0;
    int total = end1 - beg0;
    float a0 = bf16_to_f32(hs[n0 * 64 + d]);        // self-loop node0
    float a1 = bf16_to_f32(hs[(n0 + 1) * 64 + d]);  // self-loop node1
    float b0 = 0.0f, b1 = 0.0f;
    int base = 0;
    while (base < total) {
        int n = (total - base < 64) ? (total - base) : 64;
        int idx = (d < n) ? (int)csr[beg0 + base + d] : 0;
        int split = deg0 - base;
        if (split < 0) split = 0;
        if (split > n) split = n;
        int j = 0;
        for (; j + 2 <= split; j += 2) {
            int s0 = __shfl(idx, j);
            int s1 = __shfl(idx, j + 1);
            a0 += bf16_to_f32(hs[s0 * 64 + d]);
            b0 += bf16_to_f32(hs[s1 * 64 + d]);
        }
        if (j < split) { a0 += bf16_to_f32(hs[__shfl(idx, j) * 64 + d]); ++j; }
        for (; j + 2 <= n; j += 2) {
            int s0 = __shfl(idx, j);
            int s1 = __shfl(idx, j + 1);
            a1 += bf16_to_f32(hs[s0 * 64 + d]);
            b1 += bf16_to_f32(hs[s1 * 64 + d]);
        }
        if (j < n) a1 += bf16_to_f32(hs[__shfl(idx, j) * 64 + d]);
        base += n;
    }
    out0 = a0 + b0;
    out1 = a1 + b1;
}

// Layer 1 fused: gather+tanh (2 nodes/wave) -> per-wave LDS stage -> @W2*dinv -> bf16.
// W2 column in registers; h read back as float4 broadcasts (16 ds_read_b128/node).
// No __syncthreads: waves fully independent.
__global__ __launch_bounds__(256) void gather_l1_fused(const int* __restrict__ rowStart,
                                                       const u16* __restrict__ csr,
                                                       const u16* __restrict__ hs,
                                                       const float* __restrict__ dinv,
                                                       const float* __restrict__ b1,
                                                       const float* __restrict__ W2,
                                                       u16* __restrict__ hs_out) {
    __shared__ __align__(16) float hb[4][2][64];
    int tid = threadIdx.x;
    int r = tid >> 6, d = tid & 63;
    int n0 = blockIdx.x * 8 + r * 2;  // NN = 50000 = 6250*8, always in range

    float g0, g1;
    gather2(rowStart, csr, hs, n0, d, g0, g1);

    // epilogue operands (loaded after gather to keep gather-phase VGPRs low)
    float w[64];
#pragma unroll
    for (int k = 0; k < 64; ++k) w[k] = W2[k * 64 + d];
    float dv0 = dinv[n0], dv1 = dinv[n0 + 1];
    float bd = b1[d];

    hb[r][0][d] = tanhf(g0 * dv0 + bd);
    hb[r][1][d] = tanhf(g1 * dv1 + bd);
    __builtin_amdgcn_wave_barrier();  // same-wave DS ordering only

    float acc0 = 0.0f, acc1 = 0.0f;
#pragma unroll
    for (int k4 = 0; k4 < 16; ++k4) {
        float4 h0 = *(const float4*)&hb[r][0][k4 * 4];
        float4 h1 = *(const float4*)&hb[r][1][k4 * 4];
        acc0 += h0.x * w[k4 * 4] + h0.y * w[k4 * 4 + 1] + h0.z * w[k4 * 4 + 2] + h0.w * w[k4 * 4 + 3];
        acc1 += h1.x * w[k4 * 4] + h1.y * w[k4 * 4 + 1] + h1.z * w[k4 * 4 + 2] + h1.w * w[k4 * 4 + 3];
    }
    hs_out[n0 * 64 + d] = f32_to_bf16(acc0 * dv0);
    hs_out[(n0 + 1) * 64 + d] = f32_to_bf16(acc1 * dv1);
}

// Layer 2 fused: gather+tanh (2 nodes/wave) -> h_out (f32) -> classifier epilogue.
__global__ __launch_bounds__(256) void gather_l2_fused(const int* __restrict__ rowStart,
                                                       const u16* __restrict__ csr,
                                                       const u16* __restrict__ hs,
                                                       const float* __restrict__ dinv,
                                                       const float* __restrict__ b2,
                                                       const float* __restrict__ Wc,
                                                       const float* __restrict__ bc,
                                                       float* __restrict__ h_out,
                                                       float* __restrict__ out) {
    __shared__ __align__(16) float hb[4][2][64];
    int tid = threadIdx.x;
    int r = tid >> 6, d = tid & 63;
    int n0 = blockIdx.x * 8 + r * 2;

    float g0, g1;
    gather2(rowStart, csr, hs, n0, d, g0, g1);

    int dc = (d < NC) ? d : NC - 1;  // lanes >= 40 compute a dummy column
    float w[64];
#pragma unroll
    for (int k = 0; k < 64; ++k) w[k] = Wc[k * NC + dc];
    float dv0 = dinv[n0], dv1 = dinv[n0 + 1];
    float bd = b2[d];
    float bcd = bc[dc];

    float h0 = tanhf(g0 * dv0 + bd);
    float h1 = tanhf(g1 * dv1 + bd);
    h_out[n0 * 64 + d] = h0;
    h_out[(n0 + 1) * 64 + d] = h1;
    hb[r][0][d] = h0;
    hb[r][1][d] = h1;
    __builtin_amdgcn_wave_barrier();

    float acc0 = bcd, acc1 = bcd;
#pragma unroll
    for (int k4 = 0; k4 < 16; ++k4) {
        float4 v0 = *(const float4*)&hb[r][0][k4 * 4];
        float4 v1 = *(const float4*)&hb[r][1][k4 * 4];
        acc0 += v0.x * w[k4 * 4] + v0.y * w[k4 * 4 + 1] + v0.z * w[k4 * 4 + 2] + v0.w * w[k4 * 4 + 3];
        acc1 += v1.x * w[k4 * 4] + v1.y * w[k4 * 4 + 1] + v1.z * w[k4 * 4 + 2] + v1.w * w[k4 * 4 + 3];
    }
    if (d < NC) {
        out[n0 * NC + d] = acc0;
        out[(n0 + 1) * NC + d] = acc1;
    }
}

// ---------------- launch ----------------

extern "C" void kernel_launch(void* const* d_in, const int* in_sizes, int n_in,
                              void* d_out, int out_size, void* d_ws, size_t ws_size,
                              hipStream_t stream) {
    const float* x  = (const float*)d_in[0];
    const int*   ei = (const int*)d_in[1];
    const float* W1 = (const float*)d_in[2];
    const float* b1 = (const float*)d_in[3];
    const float* W2 = (const float*)d_in[4];
    const float* b2 = (const float*)d_in[5];
    const float* Wc = (const float*)d_in[6];
    const float* bc = (const float*)d_in[7];

    float* out   = (float*)d_out;   // [NN, 40]
    float* h_out = out + NN * NC;   // [NN, 64]

    // workspace layout (all segments 4B-aligned; int2 loads need 8B: offsets even)
    float* dinv     = (float*)d_ws;               // NN f32
    int*   cnt      = (int*)(dinv + NN);          // NN i32
    int*   rowStart = cnt + NN;                   // NN+1 i32
    int*   partial  = rowStart + NN + 1;          // NB_SCAN i32 (+pad)
    int*   rank     = partial + NB_SCAN + 1;      // NE i32 (8B-aligned: NN even offsets)
    u16*   csr      = (u16*)(rank + NE);          // NE u16
    u16*   hsA      = csr + NE;                   // NN*D u16
    u16*   hsB      = hsA + NN * D;               // NN*D u16

    const int pairBlocks = (NE / 2 + 255) / 256;  // 2 edges/thread
    const int nodeBlocks4 = (NN + 3) / 4;         // 12500
    const int nodeBlocks8 = NN / 8;               // 6250 (NN divisible by 8)

    // CSR + normalization (reused by both layers)
    hipMemsetAsync(cnt, 0, NN * sizeof(int), stream);
    count_rank<<<pairBlocks, 256, 0, stream>>>(ei, cnt, rank);
    scan_sums<<<NB_SCAN, 256, 0, stream>>>(cnt, partial);
    scan_partials<<<1, 256, 0, stream>>>(partial);
    scan_final<<<NB_SCAN, 256, 0, stream>>>(cnt, partial, rowStart, dinv);
    fill_csr<<<pairBlocks, 256, 0, stream>>>(ei, rank, rowStart, csr);

    // layer 0 transform, then fused layer 1 and layer 2
    gemm64_bf16<<<nodeBlocks4, 256, 0, stream>>>(x, W1, dinv, hsA);
    gather_l1_fused<<<nodeBlocks8, 256, 0, stream>>>(rowStart, csr, hsA, dinv, b1, W2, hsB);
    gather_l2_fused<<<nodeBlocks8, 256, 0, stream>>>(rowStart, csr, hsB, dinv, b2, Wc, bc,
                                                     h_out, out);
}

// Round 8
// 229.181 us; speedup vs baseline: 1.1499x; 1.1499x over previous
//
#include <hip/hip_runtime.h>
#include <math.h>

#define NN 50000
#define NE 800000
#define D 64
#define NC 40
#define NB_SCAN 196  // ceil(NN/256)

typedef unsigned short u16;
typedef unsigned int u32;

__device__ __forceinline__ float bf16_to_f32(u16 u) {
    return __uint_as_float(((u32)u) << 16);
}
__device__ __forceinline__ u16 f32_to_bf16(float v) {
    u32 x = __float_as_uint(v);
    x += 0x7FFFu + ((x >> 16) & 1u);  // round-to-nearest-even
    return (u16)(x >> 16);
}
// packed u32 = two bf16: low u16 = dim 2p, high u16 = dim 2p+1
__device__ __forceinline__ float bflo(u32 v) { return __uint_as_float(v << 16); }
__device__ __forceinline__ float bfhi(u32 v) { return __uint_as_float(v & 0xffff0000u); }

// ---------------- CSR build ----------------

// rank[e] = arrival order of edge e at its destination; cnt[i] ends as in-degree.
__global__ void count_rank(const int* __restrict__ ei, int* __restrict__ cnt,
                           int* __restrict__ rank) {
    int e = (blockIdx.x * blockDim.x + threadIdx.x) * 2;
    if (e < NE) {
        int2 dd = *(const int2*)&ei[NE + e];
        int r0 = atomicAdd(&cnt[dd.x], 1);
        int r1 = atomicAdd(&cnt[dd.y], 1);
        *(int2*)&rank[e] = make_int2(r0, r1);
    }
}

// Phase A: per-block sums of 256-element chunks of cnt.
__global__ __launch_bounds__(256) void scan_sums(const int* __restrict__ cnt,
                                                 int* __restrict__ partial) {
    __shared__ int s[256];
    int t = threadIdx.x;
    int i = blockIdx.x * 256 + t;
    s[t] = (i < NN) ? cnt[i] : 0;
    __syncthreads();
    for (int off = 128; off > 0; off >>= 1) {
        if (t < off) s[t] += s[t + off];
        __syncthreads();
    }
    if (t == 0) partial[blockIdx.x] = s[0];
}

// Phase B: single small block turns partial sums into exclusive block offsets.
__global__ __launch_bounds__(256) void scan_partials(int* __restrict__ partial) {
    __shared__ int s[256];
    int t = threadIdx.x;
    int v = (t < NB_SCAN) ? partial[t] : 0;
    s[t] = v;
    __syncthreads();
    for (int off = 1; off < 256; off <<= 1) {
        int u = (t >= off) ? s[t - off] : 0;
        __syncthreads();
        s[t] += u;
        __syncthreads();
    }
    if (t < NB_SCAN) partial[t] = s[t] - v;  // exclusive
}

// Phase C: local exclusive scan + block offset; emit rowStart and dinv.
__global__ __launch_bounds__(256) void scan_final(const int* __restrict__ cnt,
                                                  const int* __restrict__ partial,
                                                  int* __restrict__ rowStart,
                                                  float* __restrict__ dinv) {
    __shared__ int s[256];
    int t = threadIdx.x;
    int i = blockIdx.x * 256 + t;
    int v = (i < NN) ? cnt[i] : 0;
    s[t] = v;
    __syncthreads();
    for (int off = 1; off < 256; off <<= 1) {
        int u = (t >= off) ? s[t - off] : 0;
        __syncthreads();
        s[t] += u;
        __syncthreads();
    }
    if (i < NN) {
        rowStart[i] = partial[blockIdx.x] + s[t] - v;
        dinv[i] = rsqrtf((float)v + 1.0f);
    }
    if (i == 0) rowStart[NN] = NE;
}

// No atomics: position = rowStart[dst] + rank[e]. 2 edges/thread.
__global__ void fill_csr(const int* __restrict__ ei, const int* __restrict__ rank,
                         const int* __restrict__ rowStart, u16* __restrict__ csr) {
    int e = (blockIdx.x * blockDim.x + threadIdx.x) * 2;
    if (e < NE) {
        int2 ss = *(const int2*)&ei[e];
        int2 tt = *(const int2*)&ei[NE + e];
        int2 rr = *(const int2*)&rank[e];
        csr[rowStart[tt.x] + rr.x] = (u16)ss.x;
        csr[rowStart[tt.y] + rr.y] = (u16)ss.y;
    }
}

// ---------------- layer-0 dense transform ----------------

// C[row,:] = bf16( (A[row,:] @ W) * dinv[row] )
__global__ __launch_bounds__(256) void gemm64_bf16(const float* __restrict__ A,
                                                   const float* __restrict__ W,
                                                   const float* __restrict__ dinv,
                                                   u16* __restrict__ C) {
    __shared__ float Ws[64 * 64];
    __shared__ float As[4 * 64];
    int tid = threadIdx.x;
    for (int i = tid; i < 64 * 64; i += 256) Ws[i] = W[i];
    int r = tid >> 6, c = tid & 63;
    int row = blockIdx.x * 4 + r;
    if (row < NN) As[r * 64 + c] = A[row * 64 + c];
    __syncthreads();
    if (row < NN) {
        float acc = 0.0f;
#pragma unroll
        for (int k = 0; k < 64; ++k) acc += As[r * 64 + k] * Ws[k * 64 + c];
        C[row * 64 + c] = f32_to_bf16(acc * dinv[row]);
    }
}

// ---------------- gather core ----------------

// Half-wave gather: lanes 0-31 own node n0, lanes 32-63 own n0+1. Lane holds
// dims (2p, 2p+1) packed as u32 -> one wave load instruction fetches 2 full rows.
// Indices staged CSR->LDS per 32-chunk; consume is an 8-deep staged batch:
// 8 independent loads in flight, then 8 masked accumulates.
__device__ __forceinline__ void gather_pair(const int* __restrict__ rowStart,
                                            const u16* __restrict__ csr,
                                            const u32* __restrict__ hs32,
                                            int n0, int half, int p,
                                            u32* __restrict__ idxh,  // 32 slots (this wave+half)
                                            float& ox, float& oy) {
    int rs0 = rowStart[n0], rs1 = rowStart[n0 + 1], rs2 = rowStart[n0 + 2];
    int node = n0 + half;
    int beg = half ? rs1 : rs0;
    int deg = half ? (rs2 - rs1) : (rs1 - rs0);
    int d0 = rs1 - rs0, d1 = rs2 - rs1;
    int degmax = (d0 > d1) ? d0 : d1;  // wave-uniform

    u32 sv = hs32[node * 32 + p];  // self-loop row
    float ax = bflo(sv), ay = bfhi(sv);
    float bx = 0.0f, by = 0.0f;

    for (int base = 0; base < degmax; base += 32) {
        int slot = base + p;
        idxh[p] = (slot < deg) ? (u32)csr[beg + slot] : (u32)node;  // clamp -> self (safe addr)
        __builtin_amdgcn_wave_barrier();
        int n = degmax - base;
        if (n > 32) n = 32;
        for (int m0 = 0; m0 < n; m0 += 8) {  // uniform bound
            u32 st[8];
#pragma unroll
            for (int u = 0; u < 8; ++u) {
                int src = (int)idxh[m0 + u];       // LDS broadcast (per half)
                st[u] = hs32[src * 32 + p];        // independent -> 8 in flight
            }
#pragma unroll
            for (int u = 0; u < 8; ++u) {
                bool act = (base + m0 + u) < deg;
                float vx = act ? bflo(st[u]) : 0.0f;
                float vy = act ? bfhi(st[u]) : 0.0f;
                if (u & 1) { bx += vx; by += vy; } else { ax += vx; ay += vy; }
            }
        }
        __builtin_amdgcn_wave_barrier();  // protect idxh before next preload
    }
    ox = ax + bx;
    oy = ay + by;
}

// ---------------- fused gather kernels ----------------

// Layer 1: gather+tanh (2 nodes/wave, half-wave layout) -> per-wave LDS stage
// -> h1 @ W2 * dinv -> bf16. Single __syncthreads (weight staging) only.
__global__ __launch_bounds__(256) void gather_l1_fused(const int* __restrict__ rowStart,
                                                       const u16* __restrict__ csr,
                                                       const u16* __restrict__ hs,
                                                       const float* __restrict__ dinv,
                                                       const float* __restrict__ b1,
                                                       const float* __restrict__ W2,
                                                       u16* __restrict__ hs_out) {
    __shared__ float Ws[64 * 64];
    __shared__ __align__(16) float hb[4][2][64];
    __shared__ u32 idxb[4][2][32];
    int tid = threadIdx.x;
    for (int i = tid; i < 64 * 64; i += 256) Ws[i] = W2[i];
    __syncthreads();

    int r = tid >> 6, l = tid & 63, half = l >> 5, p = l & 31;
    int n0 = (blockIdx.x * 4 + r) * 2;  // NN divisible by 8
    int node = n0 + half;

    float gx, gy;
    gather_pair(rowStart, csr, (const u32*)hs, n0, half, p, idxb[r][half], gx, gy);

    float dv = dinv[node];
    float2 bb = *(const float2*)&b1[2 * p];
    float hx = tanhf(gx * dv + bb.x);
    float hy = tanhf(gy * dv + bb.y);
    *(float2*)&hb[r][half][2 * p] = make_float2(hx, hy);
    __builtin_amdgcn_wave_barrier();

    // epilogue: lane d computes output dim d for both nodes
    int d = l;
    float dv0 = dinv[n0], dv1 = dinv[n0 + 1];
    float acc0 = 0.0f, acc1 = 0.0f;
#pragma unroll
    for (int k4 = 0; k4 < 16; ++k4) {
        float4 h0 = *(const float4*)&hb[r][0][k4 * 4];
        float4 h1 = *(const float4*)&hb[r][1][k4 * 4];
        float w0 = Ws[(k4 * 4 + 0) * 64 + d];
        float w1 = Ws[(k4 * 4 + 1) * 64 + d];
        float w2 = Ws[(k4 * 4 + 2) * 64 + d];
        float w3 = Ws[(k4 * 4 + 3) * 64 + d];
        acc0 += h0.x * w0 + h0.y * w1 + h0.z * w2 + h0.w * w3;
        acc1 += h1.x * w0 + h1.y * w1 + h1.z * w2 + h1.w * w3;
    }
    hs_out[n0 * 64 + d] = f32_to_bf16(acc0 * dv0);
    hs_out[(n0 + 1) * 64 + d] = f32_to_bf16(acc1 * dv1);
}

// Layer 2: gather+tanh -> h_out (f32, coalesced float2) -> classifier epilogue.
__global__ __launch_bounds__(256) void gather_l2_fused(const int* __restrict__ rowStart,
                                                       const u16* __restrict__ csr,
                                                       const u16* __restrict__ hs,
                                                       const float* __restrict__ dinv,
                                                       const float* __restrict__ b2,
                                                       const float* __restrict__ Wc,
                                                       const float* __restrict__ bc,
                                                       float* __restrict__ h_out,
                                                       float* __restrict__ out) {
    __shared__ float Ws[64 * NC];
    __shared__ float bs[NC];
    __shared__ __align__(16) float hb[4][2][64];
    __shared__ u32 idxb[4][2][32];
    int tid = threadIdx.x;
    for (int i = tid; i < 64 * NC; i += 256) Ws[i] = Wc[i];
    if (tid < NC) bs[tid] = bc[tid];
    __syncthreads();

    int r = tid >> 6, l = tid & 63, half = l >> 5, p = l & 31;
    int n0 = (blockIdx.x * 4 + r) * 2;
    int node = n0 + half;

    float gx, gy;
    gather_pair(rowStart, csr, (const u32*)hs, n0, half, p, idxb[r][half], gx, gy);

    float dv = dinv[node];
    float2 bb = *(const float2*)&b2[2 * p];
    float hx = tanhf(gx * dv + bb.x);
    float hy = tanhf(gy * dv + bb.y);
    *(float2*)&h_out[node * 64 + 2 * p] = make_float2(hx, hy);  // both rows contiguous
    *(float2*)&hb[r][half][2 * p] = make_float2(hx, hy);
    __builtin_amdgcn_wave_barrier();

    int d = l;
    int dc = (d < NC) ? d : NC - 1;
    float acc0 = bs[dc], acc1 = bs[dc];
#pragma unroll
    for (int k4 = 0; k4 < 16; ++k4) {
        float4 v0 = *(const float4*)&hb[r][0][k4 * 4];
        float4 v1 = *(const float4*)&hb[r][1][k4 * 4];
        float w0 = Ws[(k4 * 4 + 0) * NC + dc];
        float w1 = Ws[(k4 * 4 + 1) * NC + dc];
        float w2 = Ws[(k4 * 4 + 2) * NC + dc];
        float w3 = Ws[(k4 * 4 + 3) * NC + dc];
        acc0 += v0.x * w0 + v0.y * w1 + v0.z * w2 + v0.w * w3;
        acc1 += v1.x * w0 + v1.y * w1 + v1.z * w2 + v1.w * w3;
    }
    if (d < NC) {
        out[n0 * NC + d] = acc0;
        out[(n0 + 1) * NC + d] = acc1;
    }
}

// ---------------- launch ----------------

extern "C" void kernel_launch(void* const* d_in, const int* in_sizes, int n_in,
                              void* d_out, int out_size, void* d_ws, size_t ws_size,
                              hipStream_t stream) {
    const float* x  = (const float*)d_in[0];
    const int*   ei = (const int*)d_in[1];
    const float* W1 = (const float*)d_in[2];
    const float* b1 = (const float*)d_in[3];
    const float* W2 = (const float*)d_in[4];
    const float* b2 = (const float*)d_in[5];
    const float* Wc = (const float*)d_in[6];
    const float* bc = (const float*)d_in[7];

    float* out   = (float*)d_out;   // [NN, 40]
    float* h_out = out + NN * NC;   // [NN, 64]

    // workspace layout (int2 loads need 8B alignment: all offsets even)
    float* dinv     = (float*)d_ws;               // NN f32
    int*   cnt      = (int*)(dinv + NN);          // NN i32
    int*   rowStart = cnt + NN;                   // NN+1 i32
    int*   partial  = rowStart + NN + 1;          // NB_SCAN i32 (+pad)
    int*   rank     = partial + NB_SCAN + 1;      // NE i32
    u16*   csr      = (u16*)(rank + NE);          // NE u16
    u16*   hsA      = csr + NE;                   // NN*D u16 (4B-aligned: NE even)
    u16*   hsB      = hsA + NN * D;               // NN*D u16

    const int pairBlocks = (NE / 2 + 255) / 256;  // 2 edges/thread
    const int nodeBlocks4 = (NN + 3) / 4;         // 12500
    const int nodeBlocks8 = NN / 8;               // 6250

    // CSR + normalization (reused by both layers)
    hipMemsetAsync(cnt, 0, NN * sizeof(int), stream);
    count_rank<<<pairBlocks, 256, 0, stream>>>(ei, cnt, rank);
    scan_sums<<<NB_SCAN, 256, 0, stream>>>(cnt, partial);
    scan_partials<<<1, 256, 0, stream>>>(partial);
    scan_final<<<NB_SCAN, 256, 0, stream>>>(cnt, partial, rowStart, dinv);
    fill_csr<<<pairBlocks, 256, 0, stream>>>(ei, rank, rowStart, csr);

    // layer 0 transform, then fused layer 1 and layer 2
    gemm64_bf16<<<nodeBlocks4, 256, 0, stream>>>(x, W1, dinv, hsA);
    gather_l1_fused<<<nodeBlocks8, 256, 0, stream>>>(rowStart, csr, hsA, dinv, b1, W2, hsB);
    gather_l2_fused<<<nodeBlocks8, 256, 0, stream>>>(rowStart, csr, hsB, dinv, b2, Wc, bc,
                                                     h_out, out);
}